// Round 9
// baseline (255.564 us; speedup 1.0000x reference)
//
#include <hip/hip_runtime.h>
#include <math.h>

#define NBLOCKS 2048
#define BS 256
#define K 16         // float4s per thread; NBLOCKS*BS*K == N/4 == 2^23
#define P2BS 1024    // pass2 block size

typedef float __attribute__((ext_vector_type(4))) vfloat4;
typedef int   __attribute__((ext_vector_type(4))) vint4;

// Opaque non-temporal 16B loads: issued back-to-back, no compiler-inserted
// waitcnt between them -> 32 loads (32 KB/wave) genuinely in flight.
__device__ __forceinline__ void ld_nt_f4(const vfloat4* p, vfloat4& d) {
    asm volatile("global_load_dwordx4 %0, %1, off nt" : "=v"(d) : "v"(p));
}
__device__ __forceinline__ void ld_nt_i4(const vint4* p, vint4& d) {
    asm volatile("global_load_dwordx4 %0, %1, off nt" : "=v"(d) : "v"(p));
}

// Partials layout in d_ws (doubles):
// [0*NBLOCKS..) sum_all  [1*NBLOCKS..) sum0  [2*NBLOCKS..) cnt0
// [3*NBLOCKS..) min      [4*NBLOCKS..) max

__global__ __launch_bounds__(BS) void risk_pass1(const float* __restrict__ x,
                                                 const int* __restrict__ y,
                                                 double* __restrict__ ws) {
    const vfloat4* __restrict__ x4 = (const vfloat4*)x;
    const vint4*   __restrict__ y4 = (const vint4*)y;

    // Block-contiguous: block b owns float4 range [b*BS*K, (b+1)*BS*K) (64 KB x + 64 KB y).
    const int base = blockIdx.x * (BS * K) + threadIdx.x;

    vfloat4 v0, v1, v2, v3, v4, v5, v6, v7, v8, v9, v10, v11, v12, v13, v14, v15;
    vint4   w0, w1, w2, w3, w4, w5, w6, w7, w8, w9, w10, w11, w12, w13, w14, w15;

    // Batch-issue: 16 x-loads, then 16 y-loads (order matters for the split drain).
#define LDX(i) ld_nt_f4(&x4[base + i * BS], v##i)
#define LDY(i) ld_nt_i4(&y4[base + i * BS], w##i)
    LDX(0); LDX(1); LDX(2); LDX(3); LDX(4); LDX(5); LDX(6); LDX(7);
    LDX(8); LDX(9); LDX(10); LDX(11); LDX(12); LDX(13); LDX(14); LDX(15);
    LDY(0); LDY(1); LDY(2); LDY(3); LDY(4); LDY(5); LDY(6); LDY(7);
    LDY(8); LDY(9); LDY(10); LDY(11); LDY(12); LDY(13); LDY(14); LDY(15);
#undef LDX
#undef LDY

    // Split drain 1: x loads complete (16 y loads still in flight).
    asm volatile("s_waitcnt vmcnt(16)"
                 : "+v"(v0), "+v"(v1), "+v"(v2), "+v"(v3),
                   "+v"(v4), "+v"(v5), "+v"(v6), "+v"(v7),
                   "+v"(v8), "+v"(v9), "+v"(v10), "+v"(v11),
                   "+v"(v12), "+v"(v13), "+v"(v14), "+v"(v15));

    const vfloat4 vv[K] = {v0, v1, v2, v3, v4, v5, v6, v7,
                           v8, v9, v10, v11, v12, v13, v14, v15};

    // x-only statistics computed UNDER the outstanding y loads.
    float fs[K], fmn[K], fmx[K];
    #pragma unroll
    for (int q = 0; q < K; ++q) {
        vfloat4 v = vv[q];
        fs[q]  = (v.x + v.y) + (v.z + v.w);
        fmn[q] = fminf(fminf(v.x, v.y), fminf(v.z, v.w));
        fmx[q] = fmaxf(fmaxf(v.x, v.y), fmaxf(v.z, v.w));
    }
    float s8[8], m8[8], M8[8];
    #pragma unroll
    for (int q = 0; q < 8; ++q) {
        s8[q] = fs[2 * q] + fs[2 * q + 1];
        m8[q] = fminf(fmn[2 * q], fmn[2 * q + 1]);
        M8[q] = fmaxf(fmx[2 * q], fmx[2 * q + 1]);
    }
    float s01 = s8[0] + s8[1], s23 = s8[2] + s8[3], s45 = s8[4] + s8[5], s67 = s8[6] + s8[7];
    double sum = ((double)(s01 + s23)) + ((double)(s45 + s67));
    float mn = fminf(fminf(fminf(m8[0], m8[1]), fminf(m8[2], m8[3])),
                     fminf(fminf(m8[4], m8[5]), fminf(m8[6], m8[7])));
    float mx = fmaxf(fmaxf(fmaxf(M8[0], M8[1]), fmaxf(M8[2], M8[3])),
                     fmaxf(fmaxf(M8[4], M8[5]), fmaxf(M8[6], M8[7])));

    // Split drain 2: y loads complete.
    asm volatile("s_waitcnt vmcnt(0)"
                 : "+v"(w0), "+v"(w1), "+v"(w2), "+v"(w3),
                   "+v"(w4), "+v"(w5), "+v"(w6), "+v"(w7),
                   "+v"(w8), "+v"(w9), "+v"(w10), "+v"(w11),
                   "+v"(w12), "+v"(w13), "+v"(w14), "+v"(w15));

    const vint4 wwv[K] = {w0, w1, w2, w3, w4, w5, w6, w7,
                          w8, w9, w10, w11, w12, w13, w14, w15};

    float ft[K];
    int   fc[K];
    #pragma unroll
    for (int q = 0; q < K; ++q) {
        vfloat4 v = vv[q];
        vint4   w = wwv[q];
        float a  = (w.x == 0) ? v.x : 0.0f;
        float b  = (w.y == 0) ? v.y : 0.0f;
        float cc = (w.z == 0) ? v.z : 0.0f;
        float d  = (w.w == 0) ? v.w : 0.0f;
        ft[q] = (a + b) + (cc + d);
        fc[q] = (w.x == 0) + (w.y == 0) + (w.z == 0) + (w.w == 0);
    }
    float t8[8];
    int   c8[8];
    #pragma unroll
    for (int q = 0; q < 8; ++q) {
        t8[q] = ft[2 * q] + ft[2 * q + 1];
        c8[q] = fc[2 * q] + fc[2 * q + 1];
    }
    float t01 = t8[0] + t8[1], t23 = t8[2] + t8[3], t45 = t8[4] + t8[5], t67 = t8[6] + t8[7];
    double sum0 = ((double)(t01 + t23)) + ((double)(t45 + t67));
    int cnt0 = ((c8[0] + c8[1]) + (c8[2] + c8[3])) + ((c8[4] + c8[5]) + (c8[6] + c8[7]));

    // wave (64-lane) reduction
    for (int off = 32; off > 0; off >>= 1) {
        sum  += __shfl_down(sum,  off);
        sum0 += __shfl_down(sum0, off);
        cnt0 += __shfl_down(cnt0, off);
        mn = fminf(mn, __shfl_down(mn, off));
        mx = fmaxf(mx, __shfl_down(mx, off));
    }

    __shared__ double s_sum[BS / 64], s_sum0[BS / 64];
    __shared__ int    s_cnt[BS / 64];
    __shared__ float  s_mn[BS / 64], s_mx[BS / 64];

    int lane = threadIdx.x & 63;
    int wave = threadIdx.x >> 6;
    if (lane == 0) {
        s_sum[wave] = sum; s_sum0[wave] = sum0; s_cnt[wave] = cnt0;
        s_mn[wave] = mn; s_mx[wave] = mx;
    }
    __syncthreads();

    if (threadIdx.x == 0) {
        double bsum = s_sum[0], bsum0 = s_sum0[0];
        int bcnt = s_cnt[0];
        float bmn = s_mn[0], bmx = s_mx[0];
        #pragma unroll
        for (int w = 1; w < BS / 64; ++w) {
            bsum += s_sum[w]; bsum0 += s_sum0[w]; bcnt += s_cnt[w];
            bmn = fminf(bmn, s_mn[w]); bmx = fmaxf(bmx, s_mx[w]);
        }
        ws[0 * NBLOCKS + blockIdx.x] = bsum;
        ws[1 * NBLOCKS + blockIdx.x] = bsum0;
        ws[2 * NBLOCKS + blockIdx.x] = (double)bcnt;
        ws[3 * NBLOCKS + blockIdx.x] = (double)bmn;
        ws[4 * NBLOCKS + blockIdx.x] = (double)bmx;
    }
}

__global__ __launch_bounds__(P2BS) void risk_pass2(const double* __restrict__ ws,
                                                   float* __restrict__ out,
                                                   long long n_total) {
    double sum = 0.0, sum0 = 0.0, cnt0 = 0.0;
    double mn =  INFINITY;
    double mx = -INFINITY;

    for (int i = threadIdx.x; i < NBLOCKS; i += P2BS) {
        sum  += ws[0 * NBLOCKS + i];
        sum0 += ws[1 * NBLOCKS + i];
        cnt0 += ws[2 * NBLOCKS + i];
        mn = fmin(mn, ws[3 * NBLOCKS + i]);
        mx = fmax(mx, ws[4 * NBLOCKS + i]);
    }

    for (int off = 32; off > 0; off >>= 1) {
        sum  += __shfl_down(sum,  off);
        sum0 += __shfl_down(sum0, off);
        cnt0 += __shfl_down(cnt0, off);
        mn = fmin(mn, __shfl_down(mn, off));
        mx = fmax(mx, __shfl_down(mx, off));
    }

    __shared__ double s_sum[P2BS / 64], s_sum0[P2BS / 64], s_cnt[P2BS / 64];
    __shared__ double s_mn[P2BS / 64], s_mx[P2BS / 64];
    int lane = threadIdx.x & 63;
    int wave = threadIdx.x >> 6;
    if (lane == 0) {
        s_sum[wave] = sum; s_sum0[wave] = sum0; s_cnt[wave] = cnt0;
        s_mn[wave] = mn; s_mx[wave] = mx;
    }
    __syncthreads();

    if (threadIdx.x == 0) {
        double tsum = s_sum[0], tsum0 = s_sum0[0], tcnt0 = s_cnt[0];
        double tmn = s_mn[0], tmx = s_mx[0];
        #pragma unroll
        for (int w = 1; w < P2BS / 64; ++w) {
            tsum += s_sum[w]; tsum0 += s_sum0[w]; tcnt0 += s_cnt[w];
            tmn = fmin(tmn, s_mn[w]); tmx = fmax(tmx, s_mx[w]);
        }
        double range = tmx - tmn;
        double n1 = (double)n_total - tcnt0;
        double sum1 = tsum - tsum0;
        double m0 = (tsum0 / tcnt0 - tmn) / range;
        double m1 = (sum1  / n1    - tmn) / range;
        double l = fmin(m0, m1) - fmax(m0, m1);  // = -|m0 - m1|
        out[0] = (float)l;
    }
}

extern "C" void kernel_launch(void* const* d_in, const int* in_sizes, int n_in,
                              void* d_out, int out_size, void* d_ws, size_t ws_size,
                              hipStream_t stream) {
    const float* x = (const float*)d_in[0];
    const int*   y = (const int*)d_in[1];
    float* out = (float*)d_out;
    double* ws = (double*)d_ws;
    long long n = (long long)in_sizes[0];  // 33554432 == NBLOCKS*BS*K*4

    risk_pass1<<<NBLOCKS, BS, 0, stream>>>(x, y, ws);
    risk_pass2<<<1, P2BS, 0, stream>>>(ws, out, n);
}